// Round 17
// baseline (511.494 us; speedup 1.0000x reference)
//
#include <hip/hip_runtime.h>
#include <hip/hip_bf16.h>

#define HEADS 8
#define NTOK 64
#define DIM 256

typedef __attribute__((ext_vector_type(8))) short bf16x8;
typedef __attribute__((ext_vector_type(4))) short bf16x4;
typedef __attribute__((ext_vector_type(4))) float f32x4;
typedef unsigned short u16;

__device__ __forceinline__ u16 nf2bf(float f) {
    __hip_bfloat16 b = __float2bfloat16(f);
    return *reinterpret_cast<u16*>(&b);
}

// ---------------- prep: weights fp32->bf16, fused bias table ----------------
// bias pre-multiplied by log2(e): kernel softmax uses exp2 directly.
__global__ void prep_kernel(const float* __restrict__ wqkv,
                            const float* __restrict__ wproj,
                            const float* __restrict__ table,
                            const int* __restrict__ rel_index,
                            const float* __restrict__ mask,
                            u16* __restrict__ wq_bf,
                            u16* __restrict__ wp_bf,
                            float* __restrict__ bias) {
    const int NQ = 768 * 256;
    const int NP = 256 * 256;
    const int NB = HEADS * NTOK * NTOK;
    int total = NQ + NP + NB;
    for (int i = blockIdx.x * blockDim.x + threadIdx.x; i < total;
         i += gridDim.x * blockDim.x) {
        if (i < NQ) {
            wq_bf[i] = nf2bf(wqkv[i]);
        } else if (i < NQ + NP) {
            wp_bf[i - NQ] = nf2bf(wproj[i - NQ]);
        } else {
            int j = i - (NQ + NP);          // j = h*4096 + n*64 + m
            int h = j >> 12;
            int nm = j & 4095;
            bias[j] = (table[rel_index[nm] * HEADS + h] + mask[j])
                      * 1.4426950408889634f;
        }
    }
}

// ---------------- fused window attention ----------------
// 256 threads (4 waves), 1 window/block; wave w handles heads {w, w+4}
// SEQUENTIALLY (per-head register profile identical to R16's proven one).
// KEY: __launch_bounds__(256, 1) — at 256-thread blocks, arg2=2 empirically
// caps arch VGPRs at 128 (R9/R14 spilled there); arg2=1 lifts the cap to
// 512 so the compiler allocates the ~216 this structure needs. Resources
// then permit 2 blocks/CU (LDS 67.6KBx2=135<=160; regs 2x216<=512/SIMD):
// same 8 waves/CU as R16 but in TWO INDEPENDENT barrier domains — block
// A's phase-0 HBM stalls / softmax chains overlap block B's MFMA phases.
// Inner bodies = R16 (best verified 381.8us: all-register attention, exp2
// softmax, rcp, proj-weight prefetch before B2; no setprio per R15).
__launch_bounds__(256, 1)
__global__ void win_attn_kernel(const float* __restrict__ x,
                                const u16* __restrict__ wq_bf,
                                const u16* __restrict__ wp_bf,
                                const float* __restrict__ bias,
                                const float* __restrict__ b_proj,
                                float* __restrict__ out) {
    __shared__ u16 smem[33792];          // 67,584 B
    u16* s_x = smem;                     // [64][264] x bf16
    u16* s_o = smem + 16896;             // [64][264] attention output O

    const int b = blockIdx.x;
    const int tid = threadIdx.x;
    const int w = tid >> 6;      // wave 0..3
    const int l = tid & 63;
    const int l16 = l & 15;
    const int lhi = l >> 4;

    const f32x4 zero = {0.f, 0.f, 0.f, 0.f};
    const float scale = 0.17677669529663687f * 1.4426950408889634f;

    // ---- Phase 0: load x window -> bf16 LDS ----
    const float* xw = x + (size_t)b * (NTOK * DIM);
#pragma unroll
    for (int it = 0; it < 16; ++it) {
        int idx4 = tid + it * 256;                 // float4 index 0..4095
        float4 v = reinterpret_cast<const float4*>(xw)[idx4];
        int row = idx4 >> 6;
        int col = (idx4 & 63) * 4;
        ushort4 o;
        o.x = nf2bf(v.x); o.y = nf2bf(v.y); o.z = nf2bf(v.z); o.w = nf2bf(v.w);
        *reinterpret_cast<ushort4*>(&s_x[row * 264 + col]) = o;
    }
    __syncthreads();                               // B1

    // ---- heads w and w+4, sequential; fully wave-local between barriers ----
#pragma unroll 1
    for (int hh = 0; hh < 2; ++hh) {
        const int h = w + hh * 4;

        const u16* rq0 = wq_bf + (h * 32 + l16) * 256;
        const u16* rq1 = rq0 + 16 * 256;
        const u16* rk0 = wq_bf + (256 + h * 32 + l16) * 256;
        const u16* rk1 = rk0 + 16 * 256;
        const u16* rv0 = wq_bf + (512 + h * 32 + l16) * 256;
        const u16* rv1 = rv0 + 16 * 256;

        // 2-deep weight prefetch: a* = ks, b* = ks+1
        bf16x8 aq0 = *reinterpret_cast<const bf16x8*>(rq0 + lhi * 8);
        bf16x8 aq1 = *reinterpret_cast<const bf16x8*>(rq1 + lhi * 8);
        bf16x8 ak0 = *reinterpret_cast<const bf16x8*>(rk0 + lhi * 8);
        bf16x8 ak1 = *reinterpret_cast<const bf16x8*>(rk1 + lhi * 8);
        bf16x8 av0 = *reinterpret_cast<const bf16x8*>(rv0 + lhi * 8);
        bf16x8 av1 = *reinterpret_cast<const bf16x8*>(rv1 + lhi * 8);
        bf16x8 bq0 = *reinterpret_cast<const bf16x8*>(rq0 + 32 + lhi * 8);
        bf16x8 bq1 = *reinterpret_cast<const bf16x8*>(rq1 + 32 + lhi * 8);
        bf16x8 bk0 = *reinterpret_cast<const bf16x8*>(rk0 + 32 + lhi * 8);
        bf16x8 bk1 = *reinterpret_cast<const bf16x8*>(rk1 + 32 + lhi * 8);
        bf16x8 bv0 = *reinterpret_cast<const bf16x8*>(rv0 + 32 + lhi * 8);
        bf16x8 bv1 = *reinterpret_cast<const bf16x8*>(rv1 + 32 + lhi * 8);

        // ---- Phase 1: QKV GEMM for head h ----
        // Q,K swapped: D[dim][token] (lane l16 = token, reg = dim)
        // V normal:    D[token][dim] (lane l16 = dim,   reg = token)
        f32x4 qacc[2][4], kacc[2][4], vacc[4][2];
#pragma unroll
        for (int ct = 0; ct < 2; ++ct)
#pragma unroll
            for (int tt = 0; tt < 4; ++tt) {
                qacc[ct][tt] = zero; kacc[ct][tt] = zero; vacc[tt][ct] = zero;
            }

        for (int ks = 0; ks < 8; ++ks) {
            const int k0 = ks * 32 + lhi * 8;
            bf16x8 xf[4];
#pragma unroll
            for (int tt = 0; tt < 4; ++tt)
                xf[tt] = *reinterpret_cast<const bf16x8*>(&s_x[(tt * 16 + l16) * 264 + k0]);
            bf16x8 nq0, nq1, nk0, nk1, nv0, nv1;
            if (ks < 6) {
                nq0 = *reinterpret_cast<const bf16x8*>(rq0 + k0 + 64);
                nq1 = *reinterpret_cast<const bf16x8*>(rq1 + k0 + 64);
                nk0 = *reinterpret_cast<const bf16x8*>(rk0 + k0 + 64);
                nk1 = *reinterpret_cast<const bf16x8*>(rk1 + k0 + 64);
                nv0 = *reinterpret_cast<const bf16x8*>(rv0 + k0 + 64);
                nv1 = *reinterpret_cast<const bf16x8*>(rv1 + k0 + 64);
            }
#pragma unroll
            for (int tt = 0; tt < 4; ++tt) {
                qacc[0][tt] = __builtin_amdgcn_mfma_f32_16x16x32_bf16(aq0, xf[tt], qacc[0][tt], 0, 0, 0);
                qacc[1][tt] = __builtin_amdgcn_mfma_f32_16x16x32_bf16(aq1, xf[tt], qacc[1][tt], 0, 0, 0);
                kacc[0][tt] = __builtin_amdgcn_mfma_f32_16x16x32_bf16(ak0, xf[tt], kacc[0][tt], 0, 0, 0);
                kacc[1][tt] = __builtin_amdgcn_mfma_f32_16x16x32_bf16(ak1, xf[tt], kacc[1][tt], 0, 0, 0);
                vacc[tt][0] = __builtin_amdgcn_mfma_f32_16x16x32_bf16(xf[tt], av0, vacc[tt][0], 0, 0, 0);
                vacc[tt][1] = __builtin_amdgcn_mfma_f32_16x16x32_bf16(xf[tt], av1, vacc[tt][1], 0, 0, 0);
            }
            aq0 = bq0; aq1 = bq1; ak0 = bk0; ak1 = bk1; av0 = bv0; av1 = bv1;
            bq0 = nq0; bq1 = nq1; bk0 = nk0; bk1 = nk1; bv0 = nv0; bv1 = nv1;
        }

        // Pack accumulators -> 16x16x16 fragments (layout identities):
        //  qf/kf: lane=token(n/m), k-reg=dim      (A/B of S^T-MFMA)
        //  vf:    lane=dim d,      k-reg=token m  (A of PV-MFMA)
        bf16x4 qf[4][2], kf[4][2], vf[4][2];
#pragma unroll
        for (int tt = 0; tt < 4; ++tt)
#pragma unroll
            for (int ct = 0; ct < 2; ++ct) {
                bf16x4 q, k, v;
#pragma unroll
                for (int r = 0; r < 4; ++r) {
                    q[r] = (short)nf2bf(qacc[ct][tt][r]);
                    k[r] = (short)nf2bf(kacc[ct][tt][r]);
                    v[r] = (short)nf2bf(vacc[tt][ct][r]);
                }
                qf[tt][ct] = q; kf[tt][ct] = k; vf[tt][ct] = v;
            }

        // ---- Phase 2: attention head h, fully in-register; O -> s_o ----
        const float* biash = bias + h * 4096;
        f32x4 bias_c[4], bias_n[4];
#pragma unroll
        for (int mt = 0; mt < 4; ++mt)
            bias_c[mt] = *reinterpret_cast<const f32x4*>(
                &biash[l16 * 64 + mt * 16 + lhi * 4]);

#pragma unroll
        for (int nt = 0; nt < 4; ++nt) {
            if (nt < 3) {
#pragma unroll
                for (int mt = 0; mt < 4; ++mt)
                    bias_n[mt] = *reinterpret_cast<const f32x4*>(
                        &biash[((nt + 1) * 16 + l16) * 64 + mt * 16 + lhi * 4]);
            }
            // S^T = mfma(A=K, B=Q): lane l16 = n, (lhi,reg) = m
            f32x4 sacc[4];
#pragma unroll
            for (int mt = 0; mt < 4; ++mt) {
                sacc[mt] = __builtin_amdgcn_mfma_f32_16x16x16bf16_1k(kf[mt][0], qf[nt][0], zero, 0, 0, 0);
                sacc[mt] = __builtin_amdgcn_mfma_f32_16x16x16bf16_1k(kf[mt][1], qf[nt][1], sacc[mt], 0, 0, 0);
            }
            // softmax over m: exp2, 16 in-lane adds + 2 cross-lane shuffles
            float p[4][4];
            float sum = 0.f;
#pragma unroll
            for (int mt = 0; mt < 4; ++mt)
#pragma unroll
                for (int r = 0; r < 4; ++r) {
                    // scores bounded -> exp without max-subtract
                    p[mt][r] = exp2f(sacc[mt][r] * scale + bias_c[mt][r]);
                    sum += p[mt][r];
                }
            sum += __shfl_xor(sum, 16, 64);
            sum += __shfl_xor(sum, 32, 64);
            float inv = __builtin_amdgcn_rcpf(sum);   // ~1ulp, 4x margin
            // P (unnormalized) is directly the PV B-frag: lane=n, k-reg=m
            bf16x4 pf[4];
#pragma unroll
            for (int mt = 0; mt < 4; ++mt) {
                bf16x4 pk;
#pragma unroll
                for (int r = 0; r < 4; ++r) pk[r] = (short)nf2bf(p[mt][r]);
                pf[mt] = pk;
            }
            // PV: O^T tile = sum_mt mfma(A=vf, B=pf): lane=n, reg=d
            f32x4 oa0 = zero, oa1 = zero;
#pragma unroll
            for (int mt = 0; mt < 4; ++mt) {
                oa0 = __builtin_amdgcn_mfma_f32_16x16x16bf16_1k(vf[mt][0], pf[mt], oa0, 0, 0, 0);
                oa1 = __builtin_amdgcn_mfma_f32_16x16x16bf16_1k(vf[mt][1], pf[mt], oa1, 0, 0, 0);
            }
            // O[n][d] packed writes (inv is lane-uniform)
            {
                ushort4 o0, o1;
                o0.x = nf2bf(oa0[0] * inv); o0.y = nf2bf(oa0[1] * inv);
                o0.z = nf2bf(oa0[2] * inv); o0.w = nf2bf(oa0[3] * inv);
                o1.x = nf2bf(oa1[0] * inv); o1.y = nf2bf(oa1[1] * inv);
                o1.z = nf2bf(oa1[2] * inv); o1.w = nf2bf(oa1[3] * inv);
                u16* orow = &s_o[(nt * 16 + l16) * 264 + h * 32 + lhi * 4];
                *reinterpret_cast<ushort4*>(orow) = o0;
                *reinterpret_cast<ushort4*>(orow + 16) = o1;
            }
            if (nt < 3) {
#pragma unroll
                for (int mt = 0; mt < 4; ++mt) bias_c[mt] = bias_n[mt];
            }
        }
    }

    // ---- pass-0 proj weight prefetch BEFORE the barrier (independent of O) ----
    const u16* prowA0 = wp_bf + (w * 16 + l16) * 256;
    const u16* prowA1 = wp_bf + ((w + 4) * 16 + l16) * 256;
    bf16x8 wpA0 = *reinterpret_cast<const bf16x8*>(prowA0 + lhi * 8);
    bf16x8 wpA1 = *reinterpret_cast<const bf16x8*>(prowA1 + lhi * 8);
    __syncthreads();                               // B2: all O visible

    // ---- Phase 3: proj GEMM (swapped): D[projcol][token]; 4 tiles/wave
    //      in two passes of 2 tiles (keeps register peak at R16 level) ----
    float* outw = out + (size_t)b * (NTOK * DIM);
#pragma unroll 1
    for (int pp = 0; pp < 2; ++pp) {
        const int c0 = w + pp * 8;           // col-tile indices c0, c0+4
        const u16* prow0 = (pp == 0) ? prowA0 : wp_bf + (c0 * 16 + l16) * 256;
        const u16* prow1 = (pp == 0) ? prowA1 : wp_bf + ((c0 + 4) * 16 + l16) * 256;
        bf16x8 wp0 = (pp == 0) ? wpA0 : *reinterpret_cast<const bf16x8*>(prow0 + lhi * 8);
        bf16x8 wp1 = (pp == 0) ? wpA1 : *reinterpret_cast<const bf16x8*>(prow1 + lhi * 8);

        f32x4 acc3[2][4];
#pragma unroll
        for (int t = 0; t < 2; ++t)
#pragma unroll
            for (int tt = 0; tt < 4; ++tt) acc3[t][tt] = zero;

        for (int ks = 0; ks < 8; ++ks) {
            const int k0 = ks * 32 + lhi * 8;
            bf16x8 np0, np1;
            if (ks < 7) {
                np0 = *reinterpret_cast<const bf16x8*>(prow0 + k0 + 32);
                np1 = *reinterpret_cast<const bf16x8*>(prow1 + k0 + 32);
            }
#pragma unroll
            for (int tt = 0; tt < 4; ++tt) {
                bf16x8 of = *reinterpret_cast<const bf16x8*>(&s_o[(tt * 16 + l16) * 264 + k0]);
                acc3[0][tt] = __builtin_amdgcn_mfma_f32_16x16x32_bf16(wp0, of, acc3[0][tt], 0, 0, 0);
                acc3[1][tt] = __builtin_amdgcn_mfma_f32_16x16x32_bf16(wp1, of, acc3[1][tt], 0, 0, 0);
            }
            wp0 = np0; wp1 = np1;
        }
        const float4 bpa = *reinterpret_cast<const float4*>(&b_proj[c0 * 16 + lhi * 4]);
        const float4 bpb = *reinterpret_cast<const float4*>(&b_proj[(c0 + 4) * 16 + lhi * 4]);
#pragma unroll
        for (int tt = 0; tt < 4; ++tt) {
            float4 o;
            o.x = acc3[0][tt][0] + bpa.x; o.y = acc3[0][tt][1] + bpa.y;
            o.z = acc3[0][tt][2] + bpa.z; o.w = acc3[0][tt][3] + bpa.w;
            *reinterpret_cast<float4*>(&outw[(tt * 16 + l16) * 256 + c0 * 16 + lhi * 4]) = o;
            float4 q;
            q.x = acc3[1][tt][0] + bpb.x; q.y = acc3[1][tt][1] + bpb.y;
            q.z = acc3[1][tt][2] + bpb.z; q.w = acc3[1][tt][3] + bpb.w;
            *reinterpret_cast<float4*>(&outw[(tt * 16 + l16) * 256 + (c0 + 4) * 16 + lhi * 4]) = q;
        }
    }
}

extern "C" void kernel_launch(void* const* d_in, const int* in_sizes, int n_in,
                              void* d_out, int out_size, void* d_ws, size_t ws_size,
                              hipStream_t stream) {
    const float* x     = (const float*)d_in[0];
    const float* mask  = (const float*)d_in[1];
    const float* wqkv  = (const float*)d_in[2];
    const float* wproj = (const float*)d_in[3];
    const float* bproj = (const float*)d_in[4];
    const float* table = (const float*)d_in[5];
    const int*   relix = (const int*)d_in[6];

    u16*   wq_bf = (u16*)d_ws;                 // 768*256 bf16
    u16*   wp_bf = wq_bf + 768 * 256;          // 256*256 bf16
    float* bias  = (float*)(wp_bf + 256 * 256); // 8*64*64 fp32 (pre-scaled)

    prep_kernel<<<64, 512, 0, stream>>>(wqkv, wproj, table, relix, mask,
                                        wq_bf, wp_bf, bias);
    win_attn_kernel<<<4096, 256, 0, stream>>>(x, wq_bf, wp_bf, bias, bproj,
                                              (float*)d_out);
}

// Round 18
// 379.775 us; speedup vs baseline: 1.3468x; 1.3468x over previous
//
#include <hip/hip_runtime.h>
#include <hip/hip_bf16.h>

#define HEADS 8
#define NTOK 64
#define DIM 256

typedef __attribute__((ext_vector_type(8))) short bf16x8;
typedef __attribute__((ext_vector_type(4))) short bf16x4;
typedef __attribute__((ext_vector_type(4))) float f32x4;
typedef unsigned short u16;

__device__ __forceinline__ u16 nf2bf(float f) {
    __hip_bfloat16 b = __float2bfloat16(f);
    return *reinterpret_cast<u16*>(&b);
}

// ---------------- prep: weights fp32->bf16, fused bias table ----------------
// bias pre-multiplied by log2(e): kernel softmax uses exp2 directly.
__global__ void prep_kernel(const float* __restrict__ wqkv,
                            const float* __restrict__ wproj,
                            const float* __restrict__ table,
                            const int* __restrict__ rel_index,
                            const float* __restrict__ mask,
                            u16* __restrict__ wq_bf,
                            u16* __restrict__ wp_bf,
                            float* __restrict__ bias) {
    const int NQ = 768 * 256;
    const int NP = 256 * 256;
    const int NB = HEADS * NTOK * NTOK;
    int total = NQ + NP + NB;
    for (int i = blockIdx.x * blockDim.x + threadIdx.x; i < total;
         i += gridDim.x * blockDim.x) {
        if (i < NQ) {
            wq_bf[i] = nf2bf(wqkv[i]);
        } else if (i < NQ + NP) {
            wp_bf[i - NQ] = nf2bf(wproj[i - NQ]);
        } else {
            int j = i - (NQ + NP);          // j = h*4096 + n*64 + m
            int h = j >> 12;
            int nm = j & 4095;
            bias[j] = (table[rel_index[nm] * HEADS + h] + mask[j])
                      * 1.4426950408889634f;
        }
    }
}

// ---------------- fused window attention ----------------
// FINAL (R16, session best 381.8 us): 512 threads (8 waves), 1 window/block,
// wave w = head w end-to-end, all-register attention (S computed transposed
// via mfma(K,Q) -> in-register softmax over 16 in-lane values + 2 shuffles;
// QKV accumulator layouts ARE the next MFMA's fragment layouts, so Q,K,V,P
// never round-trip through LDS). Two LDS buffers (x staging + O exchange),
// 2 barriers. exp2 softmax (log2e folded into bias+scale), v_rcp for the
// reciprocal, phase-3 weight prefetch issued before B2.
//
// Structural ceiling (verified over 17 rounds): ~216 regs/wave
// (96 AGPR acc + ~120 arch) -> 2 waves/SIMD max (512-reg pool); every
// higher-occupancy / split-domain / fused-ILP variant spilled or starved
// (R5/R8/R9/R10/R13/R14/R17). Matrix-pipe demand ~11.2k cyc/SIMD/block vs
// ~52k measured -> MfmaUtil ~17% is latency exposure at pinned occupancy,
// not a fixable counter. setprio hurts here (R15: waves re-converge at
// phase boundaries); VALU diet is off the critical path (R12: null).
__launch_bounds__(512, 2)
__global__ void win_attn_kernel(const float* __restrict__ x,
                                const u16* __restrict__ wq_bf,
                                const u16* __restrict__ wp_bf,
                                const float* __restrict__ bias,
                                const float* __restrict__ b_proj,
                                float* __restrict__ out) {
    __shared__ u16 smem[33792];          // 67,584 B
    u16* s_x = smem;                     // [64][264] x bf16
    u16* s_o = smem + 16896;             // [64][264] attention output O

    const int b = blockIdx.x;
    const int tid = threadIdx.x;
    const int w = tid >> 6;      // wave 0..7 == head
    const int l = tid & 63;
    const int l16 = l & 15;
    const int lhi = l >> 4;
    const int h = w;

    const u16* rq0 = wq_bf + (h * 32 + l16) * 256;
    const u16* rq1 = rq0 + 16 * 256;
    const u16* rk0 = wq_bf + (256 + h * 32 + l16) * 256;
    const u16* rk1 = rk0 + 16 * 256;
    const u16* rv0 = wq_bf + (512 + h * 32 + l16) * 256;
    const u16* rv1 = rv0 + 16 * 256;

    // 2-deep weight prefetch: a* = ks, b* = ks+1
    bf16x8 aq0 = *reinterpret_cast<const bf16x8*>(rq0 + lhi * 8);
    bf16x8 aq1 = *reinterpret_cast<const bf16x8*>(rq1 + lhi * 8);
    bf16x8 ak0 = *reinterpret_cast<const bf16x8*>(rk0 + lhi * 8);
    bf16x8 ak1 = *reinterpret_cast<const bf16x8*>(rk1 + lhi * 8);
    bf16x8 av0 = *reinterpret_cast<const bf16x8*>(rv0 + lhi * 8);
    bf16x8 av1 = *reinterpret_cast<const bf16x8*>(rv1 + lhi * 8);
    bf16x8 bq0 = *reinterpret_cast<const bf16x8*>(rq0 + 32 + lhi * 8);
    bf16x8 bq1 = *reinterpret_cast<const bf16x8*>(rq1 + 32 + lhi * 8);
    bf16x8 bk0 = *reinterpret_cast<const bf16x8*>(rk0 + 32 + lhi * 8);
    bf16x8 bk1 = *reinterpret_cast<const bf16x8*>(rk1 + 32 + lhi * 8);
    bf16x8 bv0 = *reinterpret_cast<const bf16x8*>(rv0 + 32 + lhi * 8);
    bf16x8 bv1 = *reinterpret_cast<const bf16x8*>(rv1 + 32 + lhi * 8);

    // ---- Phase 0: load x window -> bf16 LDS ----
    const float* xw = x + (size_t)b * (NTOK * DIM);
#pragma unroll
    for (int it = 0; it < 8; ++it) {
        int idx4 = tid + it * 512;                 // float4 index 0..4095
        float4 v = reinterpret_cast<const float4*>(xw)[idx4];
        int row = idx4 >> 6;
        int col = (idx4 & 63) * 4;
        ushort4 o;
        o.x = nf2bf(v.x); o.y = nf2bf(v.y); o.z = nf2bf(v.z); o.w = nf2bf(v.w);
        *reinterpret_cast<ushort4*>(&s_x[row * 264 + col]) = o;
    }
    __syncthreads();                               // B1

    // ---- Phase 1: per-head QKV GEMM ----
    // Q,K swapped: D[dim][token] (lane l16 = token, reg = dim)
    // V normal:    D[token][dim] (lane l16 = dim,   reg = token)
    f32x4 qacc[2][4], kacc[2][4], vacc[4][2];
    const f32x4 zero = {0.f, 0.f, 0.f, 0.f};
#pragma unroll
    for (int ct = 0; ct < 2; ++ct)
#pragma unroll
        for (int tt = 0; tt < 4; ++tt) {
            qacc[ct][tt] = zero; kacc[ct][tt] = zero; vacc[tt][ct] = zero;
        }

    for (int ks = 0; ks < 8; ++ks) {
        const int k0 = ks * 32 + lhi * 8;
        bf16x8 xf[4];
#pragma unroll
        for (int tt = 0; tt < 4; ++tt)
            xf[tt] = *reinterpret_cast<const bf16x8*>(&s_x[(tt * 16 + l16) * 264 + k0]);
        bf16x8 nq0, nq1, nk0, nk1, nv0, nv1;
        if (ks < 6) {
            nq0 = *reinterpret_cast<const bf16x8*>(rq0 + k0 + 64);
            nq1 = *reinterpret_cast<const bf16x8*>(rq1 + k0 + 64);
            nk0 = *reinterpret_cast<const bf16x8*>(rk0 + k0 + 64);
            nk1 = *reinterpret_cast<const bf16x8*>(rk1 + k0 + 64);
            nv0 = *reinterpret_cast<const bf16x8*>(rv0 + k0 + 64);
            nv1 = *reinterpret_cast<const bf16x8*>(rv1 + k0 + 64);
        }
#pragma unroll
        for (int tt = 0; tt < 4; ++tt) {
            qacc[0][tt] = __builtin_amdgcn_mfma_f32_16x16x32_bf16(aq0, xf[tt], qacc[0][tt], 0, 0, 0);
            qacc[1][tt] = __builtin_amdgcn_mfma_f32_16x16x32_bf16(aq1, xf[tt], qacc[1][tt], 0, 0, 0);
            kacc[0][tt] = __builtin_amdgcn_mfma_f32_16x16x32_bf16(ak0, xf[tt], kacc[0][tt], 0, 0, 0);
            kacc[1][tt] = __builtin_amdgcn_mfma_f32_16x16x32_bf16(ak1, xf[tt], kacc[1][tt], 0, 0, 0);
            vacc[tt][0] = __builtin_amdgcn_mfma_f32_16x16x32_bf16(xf[tt], av0, vacc[tt][0], 0, 0, 0);
            vacc[tt][1] = __builtin_amdgcn_mfma_f32_16x16x32_bf16(xf[tt], av1, vacc[tt][1], 0, 0, 0);
        }
        aq0 = bq0; aq1 = bq1; ak0 = bk0; ak1 = bk1; av0 = bv0; av1 = bv1;
        bq0 = nq0; bq1 = nq1; bk0 = nk0; bk1 = nk1; bv0 = nv0; bv1 = nv1;
    }

    // Pack accumulators -> 16x16x16 fragments (layout identities):
    //  qf/kf: lane=token(n/m), k-reg=dim      (A/B of S^T-MFMA)
    //  vf:    lane=dim d,      k-reg=token m  (A of PV-MFMA)
    bf16x4 qf[4][2], kf[4][2], vf[4][2];
#pragma unroll
    for (int tt = 0; tt < 4; ++tt)
#pragma unroll
        for (int ct = 0; ct < 2; ++ct) {
            bf16x4 q, k, v;
#pragma unroll
            for (int r = 0; r < 4; ++r) {
                q[r] = (short)nf2bf(qacc[ct][tt][r]);
                k[r] = (short)nf2bf(kacc[ct][tt][r]);
                v[r] = (short)nf2bf(vacc[tt][ct][r]);
            }
            qf[tt][ct] = q; kf[tt][ct] = k; vf[tt][ct] = v;
        }

    // ---- Phase 2: attention, fully in-register; O -> s_o ----
    {
        // scale pre-multiplied by log2(e); bias table already is.
        const float scale = 0.17677669529663687f * 1.4426950408889634f;
        const float* biash = bias + h * 4096;
        f32x4 bias_c[4], bias_n[4];
#pragma unroll
        for (int mt = 0; mt < 4; ++mt)
            bias_c[mt] = *reinterpret_cast<const f32x4*>(
                &biash[l16 * 64 + mt * 16 + lhi * 4]);

#pragma unroll
        for (int nt = 0; nt < 4; ++nt) {
            if (nt < 3) {
#pragma unroll
                for (int mt = 0; mt < 4; ++mt)
                    bias_n[mt] = *reinterpret_cast<const f32x4*>(
                        &biash[((nt + 1) * 16 + l16) * 64 + mt * 16 + lhi * 4]);
            }
            // S^T = mfma(A=K, B=Q): lane l16 = n, (lhi,reg) = m
            f32x4 sacc[4];
#pragma unroll
            for (int mt = 0; mt < 4; ++mt) {
                sacc[mt] = __builtin_amdgcn_mfma_f32_16x16x16bf16_1k(kf[mt][0], qf[nt][0], zero, 0, 0, 0);
                sacc[mt] = __builtin_amdgcn_mfma_f32_16x16x16bf16_1k(kf[mt][1], qf[nt][1], sacc[mt], 0, 0, 0);
            }
            // softmax over m: exp2, 16 in-lane adds + 2 cross-lane shuffles
            float p[4][4];
            float sum = 0.f;
#pragma unroll
            for (int mt = 0; mt < 4; ++mt)
#pragma unroll
                for (int r = 0; r < 4; ++r) {
                    // scores bounded -> exp without max-subtract
                    p[mt][r] = exp2f(sacc[mt][r] * scale + bias_c[mt][r]);
                    sum += p[mt][r];
                }
            sum += __shfl_xor(sum, 16, 64);
            sum += __shfl_xor(sum, 32, 64);
            float inv = __builtin_amdgcn_rcpf(sum);   // ~1ulp, 4x margin
            // P (unnormalized) is directly the PV B-frag: lane=n, k-reg=m
            bf16x4 pf[4];
#pragma unroll
            for (int mt = 0; mt < 4; ++mt) {
                bf16x4 pk;
#pragma unroll
                for (int r = 0; r < 4; ++r) pk[r] = (short)nf2bf(p[mt][r]);
                pf[mt] = pk;
            }
            // PV: O^T tile = sum_mt mfma(A=vf, B=pf): lane=n, reg=d
            f32x4 oa0 = zero, oa1 = zero;
#pragma unroll
            for (int mt = 0; mt < 4; ++mt) {
                oa0 = __builtin_amdgcn_mfma_f32_16x16x16bf16_1k(vf[mt][0], pf[mt], oa0, 0, 0, 0);
                oa1 = __builtin_amdgcn_mfma_f32_16x16x16bf16_1k(vf[mt][1], pf[mt], oa1, 0, 0, 0);
            }
            // O[n][d] packed writes (inv is lane-uniform here)
            {
                ushort4 o0, o1;
                o0.x = nf2bf(oa0[0] * inv); o0.y = nf2bf(oa0[1] * inv);
                o0.z = nf2bf(oa0[2] * inv); o0.w = nf2bf(oa0[3] * inv);
                o1.x = nf2bf(oa1[0] * inv); o1.y = nf2bf(oa1[1] * inv);
                o1.z = nf2bf(oa1[2] * inv); o1.w = nf2bf(oa1[3] * inv);
                u16* orow = &s_o[(nt * 16 + l16) * 264 + h * 32 + lhi * 4];
                *reinterpret_cast<ushort4*>(orow) = o0;
                *reinterpret_cast<ushort4*>(orow + 16) = o1;
            }
            if (nt < 3) {
#pragma unroll
                for (int mt = 0; mt < 4; ++mt) bias_c[mt] = bias_n[mt];
            }
        }
    }

    // ---- Phase 3 weight prefetch issued BEFORE the barrier (independent
    //      of O; hides one L2 round trip under the barrier drain) ----
    const u16* prow0 = wp_bf + (w * 16 + l16) * 256;
    const u16* prow1 = wp_bf + ((w + 8) * 16 + l16) * 256;
    bf16x8 wp0 = *reinterpret_cast<const bf16x8*>(prow0 + lhi * 8);
    bf16x8 wp1 = *reinterpret_cast<const bf16x8*>(prow1 + lhi * 8);
    __syncthreads();                               // B2

    // ---- Phase 3: proj GEMM (swapped): D[projcol][token]; 2 tiles/wave ----
    f32x4 acc3[2][4];
#pragma unroll
    for (int t = 0; t < 2; ++t)
#pragma unroll
        for (int tt = 0; tt < 4; ++tt) acc3[t][tt] = zero;

    for (int ks = 0; ks < 8; ++ks) {
        const int k0 = ks * 32 + lhi * 8;
        bf16x8 np0, np1;
        if (ks < 7) {
            np0 = *reinterpret_cast<const bf16x8*>(prow0 + k0 + 32);
            np1 = *reinterpret_cast<const bf16x8*>(prow1 + k0 + 32);
        }
#pragma unroll
        for (int tt = 0; tt < 4; ++tt) {
            bf16x8 of = *reinterpret_cast<const bf16x8*>(&s_o[(tt * 16 + l16) * 264 + k0]);
            acc3[0][tt] = __builtin_amdgcn_mfma_f32_16x16x32_bf16(wp0, of, acc3[0][tt], 0, 0, 0);
            acc3[1][tt] = __builtin_amdgcn_mfma_f32_16x16x32_bf16(wp1, of, acc3[1][tt], 0, 0, 0);
        }
        wp0 = np0; wp1 = np1;
    }
    float* outw = out + (size_t)b * (NTOK * DIM);
#pragma unroll
    for (int t = 0; t < 2; ++t) {
        int colb = (w + t * 8) * 16 + lhi * 4;
        float4 bp = *reinterpret_cast<const float4*>(&b_proj[colb]);
#pragma unroll
        for (int tt = 0; tt < 4; ++tt) {
            float4 o;
            o.x = acc3[t][tt][0] + bp.x;
            o.y = acc3[t][tt][1] + bp.y;
            o.z = acc3[t][tt][2] + bp.z;
            o.w = acc3[t][tt][3] + bp.w;
            *reinterpret_cast<float4*>(&outw[(tt * 16 + l16) * 256 + colb]) = o;
        }
    }
}

extern "C" void kernel_launch(void* const* d_in, const int* in_sizes, int n_in,
                              void* d_out, int out_size, void* d_ws, size_t ws_size,
                              hipStream_t stream) {
    const float* x     = (const float*)d_in[0];
    const float* mask  = (const float*)d_in[1];
    const float* wqkv  = (const float*)d_in[2];
    const float* wproj = (const float*)d_in[3];
    const float* bproj = (const float*)d_in[4];
    const float* table = (const float*)d_in[5];
    const int*   relix = (const int*)d_in[6];

    u16*   wq_bf = (u16*)d_ws;                 // 768*256 bf16
    u16*   wp_bf = wq_bf + 768 * 256;          // 256*256 bf16
    float* bias  = (float*)(wp_bf + 256 * 256); // 8*64*64 fp32 (pre-scaled)

    prep_kernel<<<256, 256, 0, stream>>>(wqkv, wproj, table, relix, mask,
                                         wq_bf, wp_bf, bias);
    win_attn_kernel<<<4096, 512, 0, stream>>>(x, wq_bf, wp_bf, bias, bproj,
                                              (float*)d_out);
}